// Round 7
// baseline (315.185 us; speedup 1.0000x reference)
//
#include <hip/hip_runtime.h>

// FNO3d forward, MI355X. Round 7:
//  - A buffer + k_fH eliminated: k_liftA/k_ptA butterfly their W-DFT into an
//    LDS A-slab, do the partial H-DFT over their 16 dy rows, and atomicAdd
//    into Bh (zeroed via hipMemsetAsync between layers).
//  - k_ptout: 2 points/thread (grid 4096) to double wave supply.
//
// Layouts:
//   x  : float [B=8][C=8][64][64][64]          (67,108,864 B)
//   Bh : float2[8][8][dx=64][ky=8][kz=4]       ( 1,048,576 B)  atomic-accumulated
//   O  : float2[8][8][kx=8][ky=8][kz=4]        (   131,072 B)

#define TWO_PI_OVER_64 0.09817477042468103

__device__ __forceinline__ float gelu_fast(float x) {
    float x2 = x * x;
    float p  = x * (1.0f + 0.044715f * x2);
    float e  = __builtin_amdgcn_exp2f(-2.3022083f * p);
    return x * __builtin_amdgcn_rcpf(1.0f + e);
}

#define BUILD_TW() \
    __shared__ float twc[64], tws[64]; \
    if (threadIdx.x < 64) { \
        double a_ = TWO_PI_OVER_64 * (double)threadIdx.x; \
        twc[threadIdx.x] = (float)cos(a_); tws[threadIdx.x] = (float)sin(a_); \
    }

// W-DFT over this lane's 4 w-points, butterfly across the 16 wq-lanes,
// lanes wq<2 deposit the row's 4 kz bins (as 2 float4) into the LDS A-slab.
__device__ __forceinline__ void a_tail_lds(
    const float v[4], const float c1[4], const float s1[4],
    const float c2[4], const float s2[4], const float c3[4], const float s3[4],
    int wq, float4* __restrict__ AslRow)   // AslRow = &Asl4[(o*16+dyl)*2]
{
    float p0  = v[0] + v[1] + v[2] + v[3];
    float ar1 = v[0]*c1[0] + v[1]*c1[1] + v[2]*c1[2] + v[3]*c1[3];
    float ai1 = -(v[0]*s1[0] + v[1]*s1[1] + v[2]*s1[2] + v[3]*s1[3]);
    float ar2 = v[0]*c2[0] + v[1]*c2[1] + v[2]*c2[2] + v[3]*c2[3];
    float ai2 = -(v[0]*s2[0] + v[1]*s2[1] + v[2]*s2[2] + v[3]*s2[3]);
    float ar3 = v[0]*c3[0] + v[1]*c3[1] + v[2]*c3[2] + v[3]*c3[3];
    float ai3 = -(v[0]*s3[0] + v[1]*s3[1] + v[2]*s3[2] + v[3]*s3[3]);
    #pragma unroll
    for (int m = 1; m < 16; m <<= 1) {
        p0  += __shfl_xor(p0,  m);
        ar1 += __shfl_xor(ar1, m);  ai1 += __shfl_xor(ai1, m);
        ar2 += __shfl_xor(ar2, m);  ai2 += __shfl_xor(ai2, m);
        ar3 += __shfl_xor(ar3, m);  ai3 += __shfl_xor(ai3, m);
    }
    if (wq < 2) {
        float4 av;
        av.x = (wq == 0) ? p0   : ar2;
        av.y = (wq == 0) ? 0.f  : ai2;
        av.z = (wq == 0) ? ar1  : ar3;
        av.w = (wq == 0) ? ai1  : ai3;
        AslRow[wq] = av;
    }
}

// Partial H-DFT over the block's 16 dy rows + atomic accumulate into Bh.
// Thread t = (o,ky,kz); Asl viewed as float2 [8][16][4].
__device__ __forceinline__ void h_partial_atomic(
    const float2* __restrict__ Asl, const float* __restrict__ twc,
    const float* __restrict__ tws, int t, int b, int dx, int dy0,
    float2* __restrict__ Bh)
{
    const int kz = t & 3, ky = (t >> 2) & 7, o = t >> 5;
    const int kyv = ky < 4 ? ky : ky + 56;
    float re = 0.f, im = 0.f;
    int ti = (kyv * dy0) & 63;
    #pragma unroll
    for (int dyl = 0; dyl < 16; ++dyl) {
        float2 a = Asl[(o * 16 + dyl) * 4 + kz];
        float cc = twc[ti], ss = tws[ti];
        re += a.x * cc + a.y * ss;   // * e^{-i phi}
        im += a.y * cc - a.x * ss;
        ti = (ti + kyv) & 63;
    }
    float* p = (float*)&Bh[(size_t)(b * 8 + o) * 2048 + dx * 32 + ky * 4 + kz];
    atomicAdd(p, re);
    atomicAdd(p + 1, im);
}

// ---------------------------------------------------------------------------
// Lift (3->8 ch) + W-DFT + partial H-DFT into Bh.
// grid 2048 = b(8)*dx(64)*dyq(4); block 256 (dyl = t>>4, wq = t&15).
// ---------------------------------------------------------------------------
__global__ __launch_bounds__(256) void k_liftA(
    const float* __restrict__ u, const float* __restrict__ fc0w,
    const float* __restrict__ fc0b, float* __restrict__ x,
    float2* __restrict__ Bh)
{
    BUILD_TW();
    __shared__ float4 Asl4[8 * 16 * 2];    // A-slab: [o][dyl][kz-pair]
    const int t = threadIdx.x, bid = blockIdx.x;
    const int b = bid >> 8, dx = (bid >> 2) & 63, dy0 = (bid & 3) * 16;
    const int dyl = t >> 4, wq = t & 15;
    const size_t sp = (size_t)dx * 4096 + (size_t)(dy0 + dyl) * 64 + wq * 4;
    float uin[3][4];
    #pragma unroll
    for (int c = 0; c < 3; ++c) {
        float4 v = *(const float4*)&u[(size_t)(b * 3 + c) * 262144 + sp];
        uin[c][0] = v.x; uin[c][1] = v.y; uin[c][2] = v.z; uin[c][3] = v.w;
    }
    __syncthreads();
    float c1[4], s1[4], c2[4], s2[4], c3[4], s3[4];
    #pragma unroll
    for (int j = 0; j < 4; ++j) {
        int w = wq * 4 + j;
        c1[j] = twc[w];             s1[j] = tws[w];
        c2[j] = twc[(2 * w) & 63];  s2[j] = tws[(2 * w) & 63];
        c3[j] = twc[(3 * w) & 63];  s3[j] = tws[(3 * w) & 63];
    }
    #pragma unroll
    for (int o = 0; o < 8; ++o) {
        float w0 = fc0w[o * 3 + 0], w1 = fc0w[o * 3 + 1], w2 = fc0w[o * 3 + 2];
        float bb = fc0b[o];
        float v[4];
        #pragma unroll
        for (int j = 0; j < 4; ++j)
            v[j] = bb + uin[0][j] * w0 + uin[1][j] * w1 + uin[2][j] * w2;
        *(float4*)&x[(size_t)(b * 8 + o) * 262144 + sp] =
            make_float4(v[0], v[1], v[2], v[3]);
        a_tail_lds(v, c1, s1, c2, s2, c3, s3, wq, &Asl4[(o * 16 + dyl) * 2]);
    }
    __syncthreads();
    h_partial_atomic((const float2*)Asl4, twc, tws, t, b, dx, dy0, Bh);
}

// ---------------------------------------------------------------------------
// D-axis DFT (into LDS) + spectral mix. grid 64 = b(8)*kx(8); block 256.
// ---------------------------------------------------------------------------
__global__ __launch_bounds__(256) void k_fDmix(
    const float2* __restrict__ Bh,
    const float2* __restrict__ w1, const float2* __restrict__ w2,
    const float2* __restrict__ w3, const float2* __restrict__ w4,
    float2* __restrict__ O)
{
    BUILD_TW();
    __shared__ float2 Cs[256];   // [c][ky][kz] = c*32 + ky*4 + kz
    const int t = threadIdx.x, bid = blockIdx.x;
    const int b = bid >> 3, kx = bid & 7;
    const int kxv = kx < 4 ? kx : kx + 56;
    __syncthreads();
    {
        int kz = t & 3, ky = (t >> 2) & 7, c = t >> 5;
        const float2* Bp = Bh + (size_t)(b * 8 + c) * 2048 + ky * 4 + kz;
        float re = 0.f, im = 0.f;
        int ti = 0;
        #pragma unroll 8
        for (int dx = 0; dx < 64; ++dx) {
            float2 v = Bp[dx * 32];
            float cc = twc[ti], ss = tws[ti];
            re += v.x * cc + v.y * ss;
            im += v.y * cc - v.x * ss;
            ti = (ti + kxv) & 63;
        }
        Cs[t] = make_float2(re, im);
    }
    __syncthreads();
    {
        int kz = t & 3, ky = (t >> 2) & 7, o = t >> 5;
        const float2* wsel = (kx < 4) ? ((ky < 4) ? w1 : w3) : ((ky < 4) ? w2 : w4);
        int kxw = kx & 3, kyw = ky & 3;
        float re = 0.f, im = 0.f;
        #pragma unroll
        for (int i = 0; i < 8; ++i) {
            float2 cv = Cs[i * 32 + ky * 4 + kz];
            float2 wv = wsel[(((size_t)(i * 8 + o) * 4 + kxw) * 4 + kyw) * 4 + kz];
            re += cv.x * wv.x - cv.y * wv.y;
            im += cv.x * wv.y + cv.y * wv.x;
        }
        O[(((size_t)(b * 8 + o) * 8 + kx) * 8 + ky) * 4 + kz] = make_float2(re, im);
    }
}

// ---------------------------------------------------------------------------
// Inverse D/H DFT in LDS + irfftW + conv + gelu + x in place + Bh partial.
// grid 2048 = b(8)*dx(64)*dyq(4); block 256 (dyl = t>>4, wq = t&15).
// ---------------------------------------------------------------------------
__global__ __launch_bounds__(256) void k_ptA(
    float* __restrict__ x, const float2* __restrict__ O,
    const float* __restrict__ cw, const float* __restrict__ cb,
    float2* __restrict__ Bh)
{
    BUILD_TW();
    __shared__ float2 Ps[256];          // [o][ky][kz]
    __shared__ float2 Qs[8 * 16 * 4];   // [o][dyl][kz]
    __shared__ float4 Asl4[8 * 16 * 2];
    const int t = threadIdx.x, bid = blockIdx.x;
    const int b = bid >> 8, dx = (bid >> 2) & 63, dy0 = (bid & 3) * 16;
    const int dyl = t >> 4, wq = t & 15;
    const size_t sp = (size_t)dx * 4096 + (size_t)(dy0 + dyl) * 64 + wq * 4;
    // ---- prefetch: all global loads issued before any barrier ----
    float4 xv[8];
    #pragma unroll
    for (int c = 0; c < 8; ++c)
        xv[c] = *(const float4*)&x[(size_t)(b * 8 + c) * 262144 + sp];
    const int pkz = t & 3, pky = (t >> 2) & 7, po = t >> 5;
    float2 ov[8];
    #pragma unroll
    for (int kxi = 0; kxi < 8; ++kxi)
        ov[kxi] = O[(((size_t)(b * 8 + po) * 8 + kxi) * 8 + pky) * 4 + pkz];
    __syncthreads();
    {   // Ps
        float re = 0.f, im = 0.f;
        #pragma unroll
        for (int kxi = 0; kxi < 8; ++kxi) {
            int kxv = kxi < 4 ? kxi : kxi + 56;
            int ti = (kxv * dx) & 63;
            float cc = twc[ti], ss = tws[ti];
            re += ov[kxi].x * cc - ov[kxi].y * ss;   // * e^{+i phi}
            im += ov[kxi].y * cc + ov[kxi].x * ss;
        }
        Ps[t] = make_float2(re, im);
    }
    __syncthreads();
    for (int it = t; it < 512; it += 256) {  // Qs
        int kz = it & 3, qdyl = (it >> 2) & 15, o = it >> 6;
        int dy = dy0 + qdyl;
        float re = 0.f, im = 0.f;
        #pragma unroll
        for (int kyi = 0; kyi < 8; ++kyi) {
            int kyv = kyi < 4 ? kyi : kyi + 56;
            int ti = (kyv * dy) & 63;
            float2 v = Ps[(o * 8 + kyi) * 4 + kz];
            float cc = twc[ti], ss = tws[ti];
            re += v.x * cc - v.y * ss;
            im += v.y * cc + v.x * ss;
        }
        Qs[(o * 16 + qdyl) * 4 + kz] = make_float2(re, im);
    }
    __syncthreads();
    float c1[4], s1[4], c2[4], s2[4], c3[4], s3[4];
    #pragma unroll
    for (int j = 0; j < 4; ++j) {
        int w = wq * 4 + j;
        c1[j] = twc[w];             s1[j] = tws[w];
        c2[j] = twc[(2 * w) & 63];  s2[j] = tws[(2 * w) & 63];
        c3[j] = twc[(3 * w) & 63];  s3[j] = tws[(3 * w) & 63];
    }
    const float invN3 = 1.0f / 262144.0f;
    #pragma unroll
    for (int o = 0; o < 8; ++o) {
        float4 qa = *(const float4*)&Qs[(o * 16 + dyl) * 4];      // q0,q1
        float4 qb = *(const float4*)&Qs[(o * 16 + dyl) * 4 + 2];  // q2,q3
        float outj[4];
        #pragma unroll
        for (int j = 0; j < 4; ++j) {
            float x1 = qa.x + 2.f * (qa.z * c1[j] - qa.w * s1[j]
                                   + qb.x * c2[j] - qb.y * s2[j]
                                   + qb.z * c3[j] - qb.w * s3[j]);
            x1 *= invN3;
            float x2 = cb[o];
            #pragma unroll
            for (int c = 0; c < 8; ++c) {
                const float* xc = &xv[c].x;
                x2 += cw[o * 8 + c] * xc[j];
            }
            outj[j] = gelu_fast(x1 + x2);
        }
        *(float4*)&x[(size_t)(b * 8 + o) * 262144 + sp] =
            make_float4(outj[0], outj[1], outj[2], outj[3]);
        a_tail_lds(outj, c1, s1, c2, s2, c3, s3, wq, &Asl4[(o * 16 + dyl) * 2]);
    }
    __syncthreads();
    h_partial_atomic((const float2*)Asl4, twc, tws, t, b, dx, dy0, Bh);
}

// ---------------------------------------------------------------------------
// Layer 3: inverse DFT + conv (no gelu) -> fc1+gelu+fc2, + hard core u*nu.
// 2 points/thread. grid 4096 = b(8)*dx(64)*dyh(8); block 256
// (dyl = t>>5 in [0,8), wp = t&31, w0 = wp*2).
// ---------------------------------------------------------------------------
__global__ __launch_bounds__(256) void k_ptout(
    const float* __restrict__ x, const float2* __restrict__ O,
    const float* __restrict__ cw, const float* __restrict__ cb,
    const float* __restrict__ u, const float* __restrict__ nu,
    const float* __restrict__ fc1w, const float* __restrict__ fc1b,
    const float* __restrict__ fc2w, const float* __restrict__ fc2b,
    float* __restrict__ out)
{
    BUILD_TW();
    __shared__ float2 Ps[256];          // [o][ky][kz]
    __shared__ float2 Qs[8 * 8 * 4];    // [o][dyl][kz]
    const int t = threadIdx.x, bid = blockIdx.x;
    const int b = bid >> 9, dx = (bid >> 3) & 63, dy0 = (bid & 7) * 8;
    const int dyl = t >> 5, wp = t & 31;
    const size_t sp = (size_t)dx * 4096 + (size_t)(dy0 + dyl) * 64 + wp * 2;
    float2 xv[8];
    #pragma unroll
    for (int c = 0; c < 8; ++c)
        xv[c] = *(const float2*)&x[(size_t)(b * 8 + c) * 262144 + sp];
    float2 uv[3];
    #pragma unroll
    for (int c = 0; c < 3; ++c)
        uv[c] = *(const float2*)&u[(size_t)(b * 3 + c) * 262144 + sp];
    const int pkz = t & 3, pky = (t >> 2) & 7, po = t >> 5;
    float2 ovv[8];
    #pragma unroll
    for (int kxi = 0; kxi < 8; ++kxi)
        ovv[kxi] = O[(((size_t)(b * 8 + po) * 8 + kxi) * 8 + pky) * 4 + pkz];
    __syncthreads();
    {
        float re = 0.f, im = 0.f;
        #pragma unroll
        for (int kxi = 0; kxi < 8; ++kxi) {
            int kxv = kxi < 4 ? kxi : kxi + 56;
            int ti = (kxv * dx) & 63;
            float cc = twc[ti], ss = tws[ti];
            re += ovv[kxi].x * cc - ovv[kxi].y * ss;
            im += ovv[kxi].y * cc + ovv[kxi].x * ss;
        }
        Ps[t] = make_float2(re, im);
    }
    __syncthreads();
    {   // Qs: 256 outputs, one per thread
        int kz = t & 3, qdyl = (t >> 2) & 7, o = t >> 5;
        int dy = dy0 + qdyl;
        float re = 0.f, im = 0.f;
        #pragma unroll
        for (int kyi = 0; kyi < 8; ++kyi) {
            int kyv = kyi < 4 ? kyi : kyi + 56;
            int ti = (kyv * dy) & 63;
            float2 v = Ps[(o * 8 + kyi) * 4 + kz];
            float cc = twc[ti], ss = tws[ti];
            re += v.x * cc - v.y * ss;
            im += v.y * cc + v.x * ss;
        }
        Qs[(o * 8 + qdyl) * 4 + kz] = make_float2(re, im);
    }
    __syncthreads();
    float c1[2], s1[2], c2[2], s2[2], c3[2], s3[2];
    #pragma unroll
    for (int j = 0; j < 2; ++j) {
        int w = wp * 2 + j;
        c1[j] = twc[w];             s1[j] = tws[w];
        c2[j] = twc[(2 * w) & 63];  s2[j] = tws[(2 * w) & 63];
        c3[j] = twc[(3 * w) & 63];  s3[j] = tws[(3 * w) & 63];
    }
    const float invN3 = 1.0f / 262144.0f;
    float vv[8][2];   // layer-3 activations (no gelu)
    #pragma unroll
    for (int o = 0; o < 8; ++o) {
        float4 qa = *(const float4*)&Qs[(o * 8 + dyl) * 4];
        float4 qb = *(const float4*)&Qs[(o * 8 + dyl) * 4 + 2];
        #pragma unroll
        for (int j = 0; j < 2; ++j) {
            float x1 = qa.x + 2.f * (qa.z * c1[j] - qa.w * s1[j]
                                   + qb.x * c2[j] - qb.y * s2[j]
                                   + qb.z * c3[j] - qb.w * s3[j]);
            x1 *= invN3;
            float x2 = cb[o];
            #pragma unroll
            for (int c = 0; c < 8; ++c) {
                const float* xc = &xv[c].x;
                x2 += cw[o * 8 + c] * xc[j];
            }
            vv[o][j] = x1 + x2;
        }
    }
    float so[6][2];
    #pragma unroll
    for (int c6 = 0; c6 < 6; ++c6)
        #pragma unroll
        for (int j = 0; j < 2; ++j) so[c6][j] = fc2b[c6];
    #pragma unroll 4
    for (int h = 0; h < 32; ++h) {
        float wr[8];
        #pragma unroll
        for (int c = 0; c < 8; ++c) wr[c] = fc1w[h * 8 + c];   // uniform -> SGPR
        const float hb = fc1b[h];
        float w2r[6];
        #pragma unroll
        for (int c6 = 0; c6 < 6; ++c6) w2r[c6] = fc2w[c6 * 32 + h];
        #pragma unroll
        for (int j = 0; j < 2; ++j) {
            float a = hb;
            #pragma unroll
            for (int c = 0; c < 8; ++c) a += vv[c][j] * wr[c];
            float g = gelu_fast(a);
            #pragma unroll
            for (int c6 = 0; c6 < 6; ++c6) so[c6][j] += g * w2r[c6];
        }
    }
    const float nuv = nu[0];
    #pragma unroll
    for (int c6 = 0; c6 < 6; ++c6) {
        float2 res;
        if (c6 < 3) {
            res.x = 0.3f * so[c6][0] + uv[c6].x * nuv;
            res.y = 0.3f * so[c6][1] + uv[c6].y * nuv;
        } else {
            res.x = 0.3f * so[c6][0];
            res.y = 0.3f * so[c6][1];
        }
        *(float2*)&out[(size_t)(b * 6 + c6) * 262144 + sp] = res;
    }
}

// pack split re/im spectral leaves into interleaved float2 (n_in==48 path)
__global__ void k_pack(const float* __restrict__ re, const float* __restrict__ im,
                       float2* __restrict__ dst)
{
    int i = blockIdx.x * 256 + threadIdx.x;
    if (i < 4096) dst[i] = make_float2(re[i], im[i]);
}

// ---------------------------------------------------------------------------
extern "C" void kernel_launch(void* const* d_in, const int* in_sizes, int n_in,
                              void* d_out, int out_size, void* d_ws, size_t ws_size,
                              hipStream_t stream)
{
    (void)out_size;
    const char* leaf[32];
    bool spec_split = false;
    const char* spec_re[16]; const char* spec_im[16];
    int src = 0;
    leaf[0] = (const char*)d_in[src++];
    leaf[1] = (const char*)d_in[src++];
    leaf[2] = (const char*)d_in[src++];
    leaf[3] = (const char*)d_in[src++];
    {
        int s = (src < n_in) ? in_sizes[src] : 4096;
        if (n_in >= 48 && s == 4096) {
            spec_split = true;
            for (int i = 0; i < 16; ++i) {
                spec_re[i] = (const char*)d_in[src++];
                spec_im[i] = (const char*)d_in[src++];
            }
        } else {
            int per;
            if (s == 4096 || s == 8192) per = 1;
            else if (s == 16384 || s == 32768) per = 4;
            else per = 16;
            for (int i = 0; i < 16; i += per) {
                const char* base = (const char*)d_in[src++];
                for (int j = 0; j < per; ++j) leaf[4 + i + j] = base + (size_t)j * 4096 * 8;
            }
        }
    }
    {
        int s = (src < n_in) ? in_sizes[src] : 64;
        if (s == 64) { for (int i = 0; i < 4; ++i) leaf[20 + i] = (const char*)d_in[src++]; }
        else { const char* base = (const char*)d_in[src++];
               for (int i = 0; i < 4; ++i) leaf[20 + i] = base + (size_t)i * 64 * 4; }
    }
    {
        int s = (src < n_in) ? in_sizes[src] : 8;
        if (s == 8) { for (int i = 0; i < 4; ++i) leaf[24 + i] = (const char*)d_in[src++]; }
        else { const char* base = (const char*)d_in[src++];
               for (int i = 0; i < 4; ++i) leaf[24 + i] = base + (size_t)i * 8 * 4; }
    }
    leaf[28] = (const char*)d_in[src++];
    leaf[29] = (const char*)d_in[src++];
    leaf[30] = (const char*)d_in[src++];
    leaf[31] = (const char*)d_in[src++];

    const float* u    = (const float*)leaf[0];
    const float* nu   = (const float*)leaf[1];
    const float* fc0w = (const float*)leaf[2];
    const float* fc0b = (const float*)leaf[3];
    const float* convw[4], *convb[4];
    for (int i = 0; i < 4; ++i) { convw[i] = (const float*)leaf[20 + i];
                                  convb[i] = (const float*)leaf[24 + i]; }
    const float* fc1w = (const float*)leaf[28];
    const float* fc1b = (const float*)leaf[29];
    const float* fc2w = (const float*)leaf[30];
    const float* fc2b = (const float*)leaf[31];

    // scratch: x | Bh | O | SP.  Fallback: Bh,SP in d_out (dead before
    // k_ptout writes it); O must stay in ws (live during k_ptout).
    const size_t szX = 67108864, szB = 1048576, szO = 131072, szSP = 524288;
    char* ws = (char*)d_ws;
    float* xbuf = (float*)ws;
    float2 *Bbuf, *Obuf, *SP;
    if (ws_size >= szX + szB + szO + szSP) {
        Bbuf = (float2*)(ws + szX);
        Obuf = (float2*)(ws + szX + szB);
        SP   = (float2*)(ws + szX + szB + szO);
    } else {
        Obuf = (float2*)(ws + szX);
        Bbuf = (float2*)d_out;
        SP   = (float2*)((char*)d_out + szB);
    }

    const float2* specw[16];
    if (spec_split) {
        for (int i = 0; i < 16; ++i) {
            hipLaunchKernelGGL(k_pack, dim3(16), dim3(256), 0, stream,
                               (const float*)spec_re[i], (const float*)spec_im[i],
                               SP + (size_t)i * 4096);
            specw[i] = SP + (size_t)i * 4096;
        }
    } else {
        for (int i = 0; i < 16; ++i) specw[i] = (const float2*)leaf[4 + i];
    }
    float* outp = (float*)d_out;

    hipMemsetAsync(Bbuf, 0, szB, stream);
    hipLaunchKernelGGL(k_liftA, dim3(2048), dim3(256), 0, stream, u, fc0w, fc0b, xbuf, Bbuf);
    for (int L = 0; L < 4; ++L) {
        hipLaunchKernelGGL(k_fDmix, dim3(64), dim3(256), 0, stream,
                           Bbuf, specw[L*4+0], specw[L*4+1], specw[L*4+2], specw[L*4+3], Obuf);
        if (L < 3) {
            hipMemsetAsync(Bbuf, 0, szB, stream);   // after fDmix read, before ptA write
            hipLaunchKernelGGL(k_ptA, dim3(2048), dim3(256), 0, stream,
                               xbuf, Obuf, convw[L], convb[L], Bbuf);
        } else {
            hipLaunchKernelGGL(k_ptout, dim3(4096), dim3(256), 0, stream,
                               xbuf, Obuf, convw[3], convb[3], u, nu,
                               fc1w, fc1b, fc2w, fc2b, outp);
        }
    }
}